// Round 1
// baseline (1025.827 us; speedup 1.0000x reference)
//
#include <hip/hip_runtime.h>

// VecLeadingZeroDetector108: X [n_rows, 108] float32 bits (exact 0.0/1.0),
// out [n_rows, 7] float32 = binary (MSB-first) index of first set bit, or
// 108 = 1101100b if the row is all zero.
//
// Strategy: thread-per-row. Rows are 108 floats = 432 B, 16B-aligned per row,
// so float4 loads are legal. Read the row in 64-B chunks (4 x float4) with
// per-lane early exit on first nonzero — with p(one)=0.03 this cuts expected
// HBM fetch from 864 MB to ~420 MB. Inputs are exactly 0.0f/1.0f so `!= 0.0f`
// reproduces the reference's soft-gate logic bit-exactly.

#define LZD_NBITS 108
#define LZD_NOUT 7

__global__ __launch_bounds__(256) void lzd108_kernel(const float* __restrict__ X,
                                                     float* __restrict__ out,
                                                     int n_rows) {
    int row = blockIdx.x * blockDim.x + threadIdx.x;
    if (row >= n_rows) return;

    const float4* p = reinterpret_cast<const float4*>(X + (size_t)row * LZD_NBITS);

    int idx = -1;

    // 6 chunks of 16 floats (96 bits), early exit per lane.
    #pragma unroll 1
    for (int c = 0; c < 6; ++c) {
        float4 v0 = p[4 * c + 0];
        float4 v1 = p[4 * c + 1];
        float4 v2 = p[4 * c + 2];
        float4 v3 = p[4 * c + 3];
        unsigned m = 0u;
        m |= (v0.x != 0.0f) ? (1u << 0)  : 0u;
        m |= (v0.y != 0.0f) ? (1u << 1)  : 0u;
        m |= (v0.z != 0.0f) ? (1u << 2)  : 0u;
        m |= (v0.w != 0.0f) ? (1u << 3)  : 0u;
        m |= (v1.x != 0.0f) ? (1u << 4)  : 0u;
        m |= (v1.y != 0.0f) ? (1u << 5)  : 0u;
        m |= (v1.z != 0.0f) ? (1u << 6)  : 0u;
        m |= (v1.w != 0.0f) ? (1u << 7)  : 0u;
        m |= (v2.x != 0.0f) ? (1u << 8)  : 0u;
        m |= (v2.y != 0.0f) ? (1u << 9)  : 0u;
        m |= (v2.z != 0.0f) ? (1u << 10) : 0u;
        m |= (v2.w != 0.0f) ? (1u << 11) : 0u;
        m |= (v3.x != 0.0f) ? (1u << 12) : 0u;
        m |= (v3.y != 0.0f) ? (1u << 13) : 0u;
        m |= (v3.z != 0.0f) ? (1u << 14) : 0u;
        m |= (v3.w != 0.0f) ? (1u << 15) : 0u;
        if (m) {
            idx = 16 * c + (__ffs(m) - 1);
            break;
        }
    }

    // Tail: bits 96..107 (3 x float4), then all-zero override -> 108.
    if (idx < 0) {
        float4 v0 = p[24];
        float4 v1 = p[25];
        float4 v2 = p[26];
        unsigned m = 0u;
        m |= (v0.x != 0.0f) ? (1u << 0)  : 0u;
        m |= (v0.y != 0.0f) ? (1u << 1)  : 0u;
        m |= (v0.z != 0.0f) ? (1u << 2)  : 0u;
        m |= (v0.w != 0.0f) ? (1u << 3)  : 0u;
        m |= (v1.x != 0.0f) ? (1u << 4)  : 0u;
        m |= (v1.y != 0.0f) ? (1u << 5)  : 0u;
        m |= (v1.z != 0.0f) ? (1u << 6)  : 0u;
        m |= (v1.w != 0.0f) ? (1u << 7)  : 0u;
        m |= (v2.x != 0.0f) ? (1u << 8)  : 0u;
        m |= (v2.y != 0.0f) ? (1u << 9)  : 0u;
        m |= (v2.z != 0.0f) ? (1u << 10) : 0u;
        m |= (v2.w != 0.0f) ? (1u << 11) : 0u;
        idx = m ? (96 + (__ffs(m) - 1)) : LZD_NBITS;
    }

    float* o = out + (size_t)row * LZD_NOUT;
    o[0] = (float)((idx >> 6) & 1);
    o[1] = (float)((idx >> 5) & 1);
    o[2] = (float)((idx >> 4) & 1);
    o[3] = (float)((idx >> 3) & 1);
    o[4] = (float)((idx >> 2) & 1);
    o[5] = (float)((idx >> 1) & 1);
    o[6] = (float)(idx & 1);
}

extern "C" void kernel_launch(void* const* d_in, const int* in_sizes, int n_in,
                              void* d_out, int out_size, void* d_ws, size_t ws_size,
                              hipStream_t stream) {
    const float* X = (const float*)d_in[0];
    float* out = (float*)d_out;
    int n_rows = in_sizes[0] / LZD_NBITS;
    int block = 256;
    int grid = (n_rows + block - 1) / block;
    lzd108_kernel<<<grid, block, 0, stream>>>(X, out, n_rows);
}